// Round 5
// baseline (182.662 us; speedup 1.0000x reference)
//
#include <hip/hip_runtime.h>
#include <math.h>

#define NQ 10
#define NL 4
#define NA (NQ * NL)
#define PI_F 3.14159265358979323846f

typedef float f32x2 __attribute__((ext_vector_type(2)));

// ---------------- packed complex arithmetic (VOP3P, HW-validated R4) ----------------
template <int SR, int SI>
__device__ __forceinline__ f32x2 cmul_sg(f32x2 c, f32x2 s) {
  f32x2 d;
  if constexpr (SR > 0) {
    asm("v_pk_mul_f32 %0, %1, %2 op_sel_hi:[0,1]"
        : "=v"(d) : "v"(c), "v"(s));
  } else {
    asm("v_pk_mul_f32 %0, %1, %2 op_sel_hi:[0,1] neg_lo:[1,0] neg_hi:[1,0]"
        : "=v"(d) : "v"(c), "v"(s));
  }
  if constexpr (SI > 0) {
    asm("v_pk_fma_f32 %0, %1, %2, %0 op_sel:[1,1,0] op_sel_hi:[1,0,1] neg_lo:[1,0,0]"
        : "+v"(d) : "v"(c), "v"(s));
  } else {
    asm("v_pk_fma_f32 %0, %1, %2, %0 op_sel:[1,1,0] op_sel_hi:[1,0,1] neg_hi:[1,0,0]"
        : "+v"(d) : "v"(c), "v"(s));
  }
  return d;
}

template <int SR, int SI>
__device__ __forceinline__ f32x2 cfma_sg(f32x2 c, f32x2 s, f32x2 acc) {
  f32x2 d;
  if constexpr (SR > 0) {
    asm("v_pk_fma_f32 %0, %1, %2, %3 op_sel_hi:[0,1,1]"
        : "=v"(d) : "v"(c), "v"(s), "v"(acc));
  } else {
    asm("v_pk_fma_f32 %0, %1, %2, %3 op_sel_hi:[0,1,1] neg_lo:[1,0,0] neg_hi:[1,0,0]"
        : "=v"(d) : "v"(c), "v"(s), "v"(acc));
  }
  if constexpr (SI > 0) {
    asm("v_pk_fma_f32 %0, %1, %2, %0 op_sel:[1,1,0] op_sel_hi:[1,0,1] neg_lo:[1,0,0]"
        : "+v"(d) : "v"(c), "v"(s));
  } else {
    asm("v_pk_fma_f32 %0, %1, %2, %0 op_sel:[1,1,0] op_sel_hi:[1,0,1] neg_hi:[1,0,0]"
        : "+v"(d) : "v"(c), "v"(s));
  }
  return d;
}

// ---------------- lane-crossing helpers ----------------
template <int CTRL>
__device__ __forceinline__ float dpp_mov(float v) {
  return __int_as_float(__builtin_amdgcn_update_dpp(
      __float_as_int(v), __float_as_int(v), CTRL, 0xF, 0xF, true));
}

// gfx950 permlane swaps (VALU pipe). s_nop 1 guards possible VALU->permlane
// wait-state requirement (Vega-DPP-style).
__device__ __forceinline__ void plswap32x2(float& a0, float& b0, float& a1, float& b1) {
  asm("s_nop 1\n\t"
      "v_permlane32_swap_b32 %0, %1\n\t"
      "v_permlane32_swap_b32 %2, %3"
      : "+v"(a0), "+v"(b0), "+v"(a1), "+v"(b1));
}
__device__ __forceinline__ void plswap16x2(float& a0, float& b0, float& a1, float& b1) {
  asm("s_nop 1\n\t"
      "v_permlane16_swap_b32 %0, %1\n\t"
      "v_permlane16_swap_b32 %2, %3"
      : "+v"(a0), "+v"(b0), "+v"(a1), "+v"(b1));
}

// xor shuffle per mask: 1,2 -> quad_perm DPP; 4 -> ds_swizzle; 8 -> row_ror:8
// DPP ((j+8)%16 == j^8); 16,32 -> mov+permlane_swap+cndmask (CONVA = probed
// swap-row convention).
template <int MASK, bool CONVA>
__device__ __forceinline__ float shfl_xor_f(float v, int lane) {
  if constexpr (MASK == 1) {
    return dpp_mov<0xB1>(v);  // quad_perm(1,0,3,2)
  } else if constexpr (MASK == 2) {
    return dpp_mov<0x4E>(v);  // quad_perm(2,3,0,1)
  } else if constexpr (MASK == 4) {
    return __int_as_float(__builtin_amdgcn_ds_swizzle(__float_as_int(v), 0x101F));
  } else if constexpr (MASK == 8) {
    return dpp_mov<0x128>(v);  // row_ror:8
  } else if constexpr (MASK == 16) {
    float t = v;
    asm("s_nop 1\n\tv_permlane16_swap_b32 %0, %1" : "+v"(v), "+v"(t));
    return (((lane & 16) != 0) == CONVA) ? v : t;
  } else {
    float t = v;
    asm("s_nop 1\n\tv_permlane32_swap_b32 %0, %1" : "+v"(v), "+v"(t));
    return (((lane & 32) != 0) == CONVA) ? v : t;
  }
}

__device__ __forceinline__ float readlane_f(float v, int l) {
  return __int_as_float(__builtin_amdgcn_readlane(__float_as_int(v), l));
}

template <bool CONVA>
__device__ __forceinline__ float wave_sum_h(float v, int lane) {
  v += shfl_xor_f<1, CONVA>(v, lane);
  v += shfl_xor_f<2, CONVA>(v, lane);
  v += shfl_xor_f<4, CONVA>(v, lane);
  v += shfl_xor_f<8, CONVA>(v, lane);
  v += shfl_xor_f<16, CONVA>(v, lane);
  v += shfl_xor_f<32, CONVA>(v, lane);
  return v;
}

// Cross gate on lane bit 5 (IS32) / bit 4 (!IS32) via permlane-swap transform:
// swap gathers lo-amps of reg pair into one VGPR set, hi-amps into the other;
// gate becomes register-local with uniform coefs; swap back. Verified to be
// correct under BOTH swap-row conventions via the CONVA role assignment.
template <bool IS32, bool CONVA>
__device__ __forceinline__ void cross_gate_swap(f32x2 (&sv)[16], f32x2 u00, f32x2 u01) {
#pragma unroll
  for (int p = 0; p < 8; ++p) {
    float ux = sv[2 * p].x, uy = sv[2 * p].y;
    float wx = sv[2 * p + 1].x, wy = sv[2 * p + 1].y;
    if constexpr (IS32) plswap32x2(ux, wx, uy, wy);
    else plswap16x2(ux, wx, uy, wy);
    f32x2 lo, hi;
    if constexpr (CONVA) { lo = f32x2{ux, uy}; hi = f32x2{wx, wy}; }
    else { lo = f32x2{wx, wy}; hi = f32x2{ux, uy}; }
    f32x2 nlo = cfma_sg<1, 1>(u01, hi, cmul_sg<1, 1>(u00, lo));
    f32x2 nhi = cfma_sg<1, -1>(u00, hi, cmul_sg<-1, 1>(u01, lo));
    float ax, ay, bx, by;
    if constexpr (CONVA) { ax = nlo.x; ay = nlo.y; bx = nhi.x; by = nhi.y; }
    else { ax = nhi.x; ay = nhi.y; bx = nlo.x; by = nlo.y; }
    if constexpr (IS32) plswap32x2(ax, bx, ay, by);
    else plswap16x2(ax, bx, ay, by);
    sv[2 * p] = f32x2{ax, ay};
    sv[2 * p + 1] = f32x2{bx, by};
  }
}

// Cross gate on lane bit LB (0..3) with per-lane A/B sign select.
template <int LB, bool CONVA>
__device__ __forceinline__ void cross_gate(f32x2 (&sv)[16], f32x2 u00, f32x2 u01,
                                           int lane) {
  const bool bit = (lane & (1 << LB)) != 0;
  const f32x2 A = {u00.x, bit ? -u00.y : u00.y};
  const f32x2 B = {bit ? -u01.x : u01.x, u01.y};
#pragma unroll
  for (int r = 0; r < 16; ++r) {
    f32x2 p;
    p.x = shfl_xor_f<(1 << LB), CONVA>(sv[r].x, lane);
    p.y = shfl_xor_f<(1 << LB), CONVA>(sv[r].y, lane);
    sv[r] = cfma_sg<1, 1>(B, p, cmul_sg<1, 1>(A, sv[r]));
  }
}

// Register-local gate on reg bit RB.
template <int RB>
__device__ __forceinline__ void local_gate(f32x2 (&sv)[16], f32x2 u00, f32x2 u01) {
#pragma unroll
  for (int rlo = 0; rlo < 16; ++rlo) {
    if (rlo & (1 << RB)) continue;
    const int rhi = rlo | (1 << RB);
    f32x2 lo = sv[rlo], hi = sv[rhi];
    sv[rlo] = cfma_sg<1, 1>(u01, hi, cmul_sg<1, 1>(u00, lo));
    sv[rhi] = cfma_sg<1, -1>(u00, hi, cmul_sg<-1, 1>(u01, lo));
  }
}

// One wave per batch element. State index i = lane*16 + r.
// Wire q at bit (9-q): wires 0..5 -> lane bits 5..0, wires 6..9 -> reg bits 3..0.
template <bool CONVA>
__device__ void simulate(const float* __restrict__ x, const float* __restrict__ w,
                         float* __restrict__ out, int wid, int lane) {
  // ---- prologue: lane j < 40 owns gate j = l*10 + q; full SU(2) coefs ----
  float U00r = 0.f, U00i = 0.f, U01r = 0.f, U01i = 0.f;
  if (lane < NA) {
    float xv = x[wid * NA + lane];
    float a = 0.5f * PI_F * atanf(xv);
    float sa, ca;
    sincosf(a, &sa, &ca);
    float w0 = w[2 * lane], w1 = w[2 * lane + 1];
    float sphi, cphi, sw, cw;
    sincosf(0.5f * w0, &sphi, &cphi);
    sincosf(0.5f * w1, &sw, &cw);
    const float Pr = cw * cphi, Pi = -cw * sphi;  // P = cos(w1/2) e^{-i w0/2}
    const float Qr = sw * cphi, Qi = sw * sphi;   // Q = sin(w1/2) e^{+i w0/2}
    U00r = ca * Pr - sa * Qr;
    U00i = ca * Pi - sa * Qi;
    U01r = -(sa * Pr + ca * Qr);
    U01i = -(sa * Pi + ca * Qi);
  }

  f32x2 sv[16];
#pragma unroll
  for (int r = 0; r < 16; ++r) sv[r] = f32x2{0.f, 0.f};
  if (lane == 0) sv[0].x = 1.f;  // |0...0>

  const int permSrc = lane ^ (lane >> 1);  // composed CNOT(q,q+1), q=0..4

#pragma unroll 1
  for (int l = 0; l < NL; ++l) {
    const int j0 = l * NQ;
#define GET_U(j)                                                      \
  const f32x2 u00 = {readlane_f(U00r, (j)), readlane_f(U00i, (j))};   \
  const f32x2 u01 = {readlane_f(U01r, (j)), readlane_f(U01i, (j))}
    { GET_U(j0 + 0); cross_gate_swap<true, CONVA>(sv, u00, u01); }   // wire0: bit5
    { GET_U(j0 + 1); cross_gate_swap<false, CONVA>(sv, u00, u01); }  // wire1: bit4
    { GET_U(j0 + 2); cross_gate<3, CONVA>(sv, u00, u01, lane); }     // wire2: bit3
    { GET_U(j0 + 3); cross_gate<2, CONVA>(sv, u00, u01, lane); }     // wire3: bit2
    { GET_U(j0 + 4); cross_gate<1, CONVA>(sv, u00, u01, lane); }     // wire4: bit1
    { GET_U(j0 + 5); cross_gate<0, CONVA>(sv, u00, u01, lane); }     // wire5: bit0
    { GET_U(j0 + 6); local_gate<3>(sv, u00, u01); }                  // wire6
    { GET_U(j0 + 7); local_gate<2>(sv, u00, u01); }                  // wire7
    { GET_U(j0 + 8); local_gate<1>(sv, u00, u01); }                  // wire8
    { GET_U(j0 + 9); local_gate<0>(sv, u00, u01); }                  // wire9
#undef GET_U

    // ---------- CNOT ring, q -> q+1 mod 10 ----------
    // q=0..4 composed: lane gather from gray(lane)
#pragma unroll
    for (int r = 0; r < 16; ++r) {
      sv[r].x = __shfl(sv[r].x, permSrc);
      sv[r].y = __shfl(sv[r].y, permSrc);
    }
    // q=5: control wire5 = lane bit0, target wire6 = reg bit3 -> cond swap r<->r^8
    {
      const bool c5 = (lane & 1) != 0;
#pragma unroll
      for (int r = 0; r < 8; ++r) {
        f32x2 a = sv[r], b = sv[r + 8];
        sv[r] = c5 ? b : a;
        sv[r + 8] = c5 ? a : b;
      }
    }
    // q=6..8 composed: register gather new[j] = old[gray(j)]
    {
      f32x2 t;
      t = sv[2]; sv[2] = sv[3]; sv[3] = t;
      t = sv[4]; sv[4] = sv[6]; sv[6] = sv[5]; sv[5] = sv[7]; sv[7] = t;
      t = sv[8]; sv[8] = sv[12]; sv[12] = sv[10]; sv[10] = sv[15]; sv[15] = t;
      t = sv[9]; sv[9] = sv[13]; sv[13] = sv[11]; sv[11] = sv[14]; sv[14] = t;
    }
    // q=9: control wire9 = reg bit0, target wire0 = lane bit5 -> odd r: xor32
#pragma unroll
    for (int r = 1; r < 16; r += 2) {
      sv[r].x = shfl_xor_f<32, CONVA>(sv[r].x, lane);
      sv[r].y = shfl_xor_f<32, CONVA>(sv[r].y, lane);
    }
  }

  // ---------- epilogue ----------
  float tot = 0.f, t0 = 0.f, t1 = 0.f, t2 = 0.f, t3 = 0.f;
#pragma unroll
  for (int r = 0; r < 16; ++r) {
    float pv = sv[r].x * sv[r].x + sv[r].y * sv[r].y;
    tot += pv;
    if (r & 1) t0 += pv;
    if (r & 2) t1 += pv;
    if (r & 4) t2 += pv;
    if (r & 8) t3 += pv;
  }
  const float S3 = wave_sum_h<CONVA>(t3, lane);
  const float S2 = wave_sum_h<CONVA>(t2, lane);
  const float S1 = wave_sum_h<CONVA>(t1, lane);
  const float S0 = wave_sum_h<CONVA>(t0, lane);
  // Walsh-Hadamard across lanes: lane L holds sum_i (-1)^popcnt(L&i) tot_i.
  float v = tot, h;
  h = shfl_xor_f<1, CONVA>(v, lane);  v = (lane & 1)  ? h - v : v + h;
  h = shfl_xor_f<2, CONVA>(v, lane);  v = (lane & 2)  ? h - v : v + h;
  h = shfl_xor_f<4, CONVA>(v, lane);  v = (lane & 4)  ? h - v : v + h;
  h = shfl_xor_f<8, CONVA>(v, lane);  v = (lane & 8)  ? h - v : v + h;
  h = shfl_xor_f<16, CONVA>(v, lane); v = (lane & 16) ? h - v : v + h;
  h = shfl_xor_f<32, CONVA>(v, lane); v = (lane & 32) ? h - v : v + h;

  float* o = out + wid * NQ;
  if (lane == 32) o[0] = v;  // wire0 sign = lane bit5
  if (lane == 16) o[1] = v;
  if (lane == 8)  o[2] = v;
  if (lane == 4)  o[3] = v;
  if (lane == 2)  o[4] = v;
  if (lane == 1)  o[5] = v;  // wire5 sign = lane bit0
  if (lane == 0) {
    o[6] = v - 2.f * S3;  // wire6 = reg bit3; v(lane0) = sum(tot)
    o[7] = v - 2.f * S2;
    o[8] = v - 2.f * S1;
    o[9] = v - 2.f * S0;
  }
}

__global__ __launch_bounds__(256, 4) void qsim_kernel(
    const float* __restrict__ x, const float* __restrict__ w,
    float* __restrict__ out, int batch) {
  const int lane = threadIdx.x & 63;
  const int wid = blockIdx.x * (blockDim.x >> 6) + (threadIdx.x >> 6);
  if (wid >= batch) return;

  // Probe the permlane32_swap row-pairing convention (wave-uniform):
  // conv A (dst upper rows <-> src lower rows): lane32 of dst gets lane0's 0.0.
  float pv = (float)lane, pt = pv;
  asm("s_nop 1\n\tv_permlane32_swap_b32 %0, %1" : "+v"(pv), "+v"(pt));
  const bool convA =
      (__builtin_amdgcn_readlane(__float_as_int(pv), 32) == 0);

  if (convA) simulate<true>(x, w, out, wid, lane);
  else       simulate<false>(x, w, out, wid, lane);
}

extern "C" void kernel_launch(void* const* d_in, const int* in_sizes, int n_in,
                              void* d_out, int out_size, void* d_ws, size_t ws_size,
                              hipStream_t stream) {
  const float* x = (const float*)d_in[0];
  const float* w = (const float*)d_in[1];
  float* out = (float*)d_out;
  const int batch = in_sizes[0] / NA;
  const int wavesPerBlock = 4;  // 256 threads
  const int blocks = (batch + wavesPerBlock - 1) / wavesPerBlock;
  qsim_kernel<<<blocks, 256, 0, stream>>>(x, w, out, batch);
}

// Round 7
// 155.652 us; speedup vs baseline: 1.1735x; 1.1735x over previous
//
#include <hip/hip_runtime.h>
#include <hip/hip_fp16.h>
#include <math.h>

#define NQ 10
#define NL 4
#define NA (NQ * NL)
#define PI_F 3.14159265358979323846f

typedef _Float16 h2 __attribute__((ext_vector_type(2)));

// ---------- packed-f16 complex helpers; amp layout: bits[15:0]=re, [31:16]=im ----------
// Modifier pattern identical to the R4 HW-validated f32 version, mnemonic swapped.
// cmul_sg<SR,SI>(c,s) = (SR*c.re, SI*c.im) complex-multiplied with s.
template <int SR, int SI>
__device__ __forceinline__ unsigned cmul_sg(unsigned c, unsigned s) {
  unsigned d;
  if constexpr (SR > 0) {
    asm("v_pk_mul_f16 %0, %1, %2 op_sel_hi:[0,1]" : "=v"(d) : "v"(c), "v"(s));
  } else {
    asm("v_pk_mul_f16 %0, %1, %2 op_sel_hi:[0,1] neg_lo:[1,0] neg_hi:[1,0]"
        : "=v"(d) : "v"(c), "v"(s));
  }
  if constexpr (SI > 0) {
    asm("v_pk_fma_f16 %0, %1, %2, %0 op_sel:[1,1,0] op_sel_hi:[1,0,1] neg_lo:[1,0,0]"
        : "+v"(d) : "v"(c), "v"(s));
  } else {
    asm("v_pk_fma_f16 %0, %1, %2, %0 op_sel:[1,1,0] op_sel_hi:[1,0,1] neg_hi:[1,0,0]"
        : "+v"(d) : "v"(c), "v"(s));
  }
  return d;
}

template <int SR, int SI>
__device__ __forceinline__ unsigned cfma_sg(unsigned c, unsigned s, unsigned acc) {
  unsigned d;
  if constexpr (SR > 0) {
    asm("v_pk_fma_f16 %0, %1, %2, %3 op_sel_hi:[0,1,1]"
        : "=v"(d) : "v"(c), "v"(s), "v"(acc));
  } else {
    asm("v_pk_fma_f16 %0, %1, %2, %3 op_sel_hi:[0,1,1] neg_lo:[1,0,0] neg_hi:[1,0,0]"
        : "=v"(d) : "v"(c), "v"(s), "v"(acc));
  }
  if constexpr (SI > 0) {
    asm("v_pk_fma_f16 %0, %1, %2, %0 op_sel:[1,1,0] op_sel_hi:[1,0,1] neg_lo:[1,0,0]"
        : "+v"(d) : "v"(c), "v"(s));
  } else {
    asm("v_pk_fma_f16 %0, %1, %2, %0 op_sel:[1,1,0] op_sel_hi:[1,0,1] neg_hi:[1,0,0]"
        : "+v"(d) : "v"(c), "v"(s));
  }
  return d;
}

// ---------- lane-crossing: masks 1,2 quad_perm DPP; 8 row_ror:8 DPP ((k+8)%16==k^8);
// 4,16 ds_swizzle; 32 __shfl_xor (ds_permute). ----------
template <int MASK>
__device__ __forceinline__ int ishfl_xor(int v) {
  if constexpr (MASK == 1) {
    return __builtin_amdgcn_update_dpp(v, v, 0xB1, 0xF, 0xF, true);
  } else if constexpr (MASK == 2) {
    return __builtin_amdgcn_update_dpp(v, v, 0x4E, 0xF, 0xF, true);
  } else if constexpr (MASK == 4) {
    return __builtin_amdgcn_ds_swizzle(v, 0x101F);
  } else if constexpr (MASK == 8) {
    return __builtin_amdgcn_update_dpp(v, v, 0x128, 0xF, 0xF, true);
  } else if constexpr (MASK == 16) {
    return __builtin_amdgcn_ds_swizzle(v, 0x401F);
  } else {
    return __shfl_xor(v, MASK, 64);
  }
}

template <int MASK>
__device__ __forceinline__ float fshfl_xor(float v) {
  return __int_as_float(ishfl_xor<MASK>(__float_as_int(v)));
}

__device__ __forceinline__ unsigned readlane_u(unsigned v, int l) {
  return (unsigned)__builtin_amdgcn_readlane((int)v, l);
}

__device__ __forceinline__ float wave_sum_h(float v) {
  v += fshfl_xor<1>(v);
  v += fshfl_xor<2>(v);
  v += fshfl_xor<4>(v);
  v += fshfl_xor<8>(v);
  v += fshfl_xor<16>(v);
  v += fshfl_xor<32>(v);
  return v;
}

// Round-to-nearest f16 pack (v_cvt_f16_f32 is RTN; cvt_pkrtz is RTZ and
// biases coefficient magnitudes down -> R6's 1.5% norm contraction).
__device__ __forceinline__ unsigned pack_h2_rtn(float re, float im) {
  return (unsigned)__half_as_ushort(__float2half(re)) |
         ((unsigned)__half_as_ushort(__float2half(im)) << 16);
}

// Cross gate on lane bit LB: pairs lane <-> lane^(1<<LB).
// A = bit ? conj(u00) : u00 (im sign = bit31); B = bit ? -re(u01) : u01 (re sign = bit15).
template <int LB>
__device__ __forceinline__ void cross_gate(unsigned (&sv)[16], unsigned u00,
                                           unsigned u01, int lane) {
  const bool bit = (lane & (1 << LB)) != 0;
  const unsigned A = bit ? (u00 ^ 0x80000000u) : u00;
  const unsigned B = bit ? (u01 ^ 0x00008000u) : u01;
#pragma unroll
  for (int r = 0; r < 16; ++r) {
    unsigned p = (unsigned)ishfl_xor<(1 << LB)>((int)sv[r]);
    sv[r] = cfma_sg<1, 1>(B, p, cmul_sg<1, 1>(A, sv[r]));
  }
}

// Register-local gate on reg bit RB:
// lo' = u00*lo + u01*hi ; hi' = -conj(u01)*lo + conj(u00)*hi
template <int RB>
__device__ __forceinline__ void local_gate(unsigned (&sv)[16], unsigned u00,
                                           unsigned u01) {
#pragma unroll
  for (int rlo = 0; rlo < 16; ++rlo) {
    if (rlo & (1 << RB)) continue;
    const int rhi = rlo | (1 << RB);
    unsigned lo = sv[rlo], hi = sv[rhi];
    sv[rlo] = cfma_sg<1, 1>(u01, hi, cmul_sg<1, 1>(u00, lo));
    sv[rhi] = cfma_sg<1, -1>(u00, hi, cmul_sg<-1, 1>(u01, lo));
  }
}

// One wave per batch element, ELEMS sequential elements per wave.
// State index i = lane*16 + r. Wire q at bit (9-q): wires 0..5 -> lane bits
// 5..0, wires 6..9 -> reg bits 3..0.
#define ELEMS 2
__global__ __launch_bounds__(256, 8) void qsim_kernel(
    const float* __restrict__ x, const float* __restrict__ w,
    float* __restrict__ out, int batch) {
  const int lane = threadIdx.x & 63;
  const int wv = blockIdx.x * (blockDim.x >> 6) + (threadIdx.x >> 6);
  const int permSrc = lane ^ (lane >> 1);  // composed CNOT(q,q+1), q=0..4

  // weight-only gate factors (shared across elements): lane j<40 owns gate j
  float Pr = 0.f, Pi = 0.f, Qr = 0.f, Qi = 0.f;
  if (lane < NA) {
    float w0 = w[2 * lane], w1 = w[2 * lane + 1];
    float sphi, cphi, sw, cw;
    sincosf(0.5f * w0, &sphi, &cphi);
    sincosf(0.5f * w1, &sw, &cw);
    Pr = cw * cphi; Pi = -cw * sphi;  // P = cos(w1/2) e^{-i w0/2}
    Qr = sw * cphi; Qi = sw * sphi;   // Q = sin(w1/2) e^{+i w0/2}
  }

#pragma unroll 1
  for (int e = 0; e < ELEMS; ++e) {
    const int wid = wv * ELEMS + e;
    if (wid >= batch) break;

    // ---- per-element gate coefs, packed to f16 (re,im) with RTN ----
    unsigned U00 = 0, U01 = 0;
    if (lane < NA) {
      float xv = x[wid * NA + lane];
      float a = 0.5f * PI_F * atanf(xv);
      float sa, ca;
      sincosf(a, &sa, &ca);
      float u00r = ca * Pr - sa * Qr;
      float u00i = ca * Pi - sa * Qi;
      float u01r = -(sa * Pr + ca * Qr);
      float u01i = -(sa * Pi + ca * Qi);
      U00 = pack_h2_rtn(u00r, u00i);
      U01 = pack_h2_rtn(u01r, u01i);
    }

    unsigned sv[16];
#pragma unroll
    for (int r = 0; r < 16; ++r) sv[r] = 0u;
    if (lane == 0) sv[0] = 0x3C00u;  // (1.0h, 0.0h) -> |0...0>

#pragma unroll 1
    for (int l = 0; l < NL; ++l) {
      const int j0 = l * NQ;
#define GET_U(j)                              \
  const unsigned u00 = readlane_u(U00, (j)); \
  const unsigned u01 = readlane_u(U01, (j))
      { GET_U(j0 + 0); cross_gate<5>(sv, u00, u01, lane); }  // wire0: lane bit5
      { GET_U(j0 + 1); cross_gate<4>(sv, u00, u01, lane); }  // wire1: lane bit4
      { GET_U(j0 + 2); cross_gate<3>(sv, u00, u01, lane); }  // wire2: lane bit3
      { GET_U(j0 + 3); cross_gate<2>(sv, u00, u01, lane); }  // wire3: lane bit2
      { GET_U(j0 + 4); cross_gate<1>(sv, u00, u01, lane); }  // wire4: lane bit1
      { GET_U(j0 + 5); cross_gate<0>(sv, u00, u01, lane); }  // wire5: lane bit0
      { GET_U(j0 + 6); local_gate<3>(sv, u00, u01); }        // wire6: reg bit3
      { GET_U(j0 + 7); local_gate<2>(sv, u00, u01); }        // wire7: reg bit2
      { GET_U(j0 + 8); local_gate<1>(sv, u00, u01); }        // wire8: reg bit1
      { GET_U(j0 + 9); local_gate<0>(sv, u00, u01); }        // wire9: reg bit0
#undef GET_U

      // ---------- CNOT ring, q -> q+1 mod 10 ----------
      // q=0..4 composed: lane gather from gray(lane)
#pragma unroll
      for (int r = 0; r < 16; ++r) sv[r] = (unsigned)__shfl((int)sv[r], permSrc);
      // q=5: control wire5 = lane bit0, target wire6 = reg bit3 -> cond swap r<->r^8
      {
        const bool c5 = (lane & 1) != 0;
#pragma unroll
        for (int r = 0; r < 8; ++r) {
          unsigned a = sv[r], b = sv[r + 8];
          sv[r] = c5 ? b : a;
          sv[r + 8] = c5 ? a : b;
        }
      }
      // q=6..8 composed: register gather new[j] = old[gray(j)]
      {
        unsigned t;
        t = sv[2]; sv[2] = sv[3]; sv[3] = t;
        t = sv[4]; sv[4] = sv[6]; sv[6] = sv[5]; sv[5] = sv[7]; sv[7] = t;
        t = sv[8]; sv[8] = sv[12]; sv[12] = sv[10]; sv[10] = sv[15]; sv[15] = t;
        t = sv[9]; sv[9] = sv[13]; sv[13] = sv[11]; sv[11] = sv[14]; sv[14] = t;
      }
      // q=9: control wire9 = reg bit0, target wire0 = lane bit5 -> odd r: xor32
#pragma unroll
      for (int r = 1; r < 16; r += 2)
        sv[r] = (unsigned)ishfl_xor<32>((int)sv[r]);
    }

    // ---------- epilogue (f32) ----------
    float tot = 0.f, t0 = 0.f, t1 = 0.f, t2 = 0.f, t3 = 0.f;
#pragma unroll
    for (int r = 0; r < 16; ++r) {
      h2 a = __builtin_bit_cast(h2, sv[r]);
      float re = (float)a.x, im = (float)a.y;
      float pv = re * re + im * im;
      tot += pv;
      if (r & 1) t0 += pv;
      if (r & 2) t1 += pv;
      if (r & 4) t2 += pv;
      if (r & 8) t3 += pv;
    }
    const float S3 = wave_sum_h(t3);
    const float S2 = wave_sum_h(t2);
    const float S1 = wave_sum_h(t1);
    const float S0 = wave_sum_h(t0);
    // Norm renormalization: true Z = (P0-P1)/(P0+P1). Cancels residual
    // contraction/expansion error of the f16 evolution.
    const float N = wave_sum_h(tot);
    const float invN = 1.0f / N;
    // Walsh-Hadamard across lanes: lane L holds sum_i (-1)^popcnt(L&i) tot_i.
    float v = tot, h;
    h = fshfl_xor<1>(v);  v = (lane & 1)  ? h - v : v + h;
    h = fshfl_xor<2>(v);  v = (lane & 2)  ? h - v : v + h;
    h = fshfl_xor<4>(v);  v = (lane & 4)  ? h - v : v + h;
    h = fshfl_xor<8>(v);  v = (lane & 8)  ? h - v : v + h;
    h = fshfl_xor<16>(v); v = (lane & 16) ? h - v : v + h;
    h = fshfl_xor<32>(v); v = (lane & 32) ? h - v : v + h;

    float* o = out + wid * NQ;
    if (lane == 32) o[0] = v * invN;  // wire0 sign = lane bit5
    if (lane == 16) o[1] = v * invN;
    if (lane == 8)  o[2] = v * invN;
    if (lane == 4)  o[3] = v * invN;
    if (lane == 2)  o[4] = v * invN;
    if (lane == 1)  o[5] = v * invN;  // wire5 sign = lane bit0
    if (lane == 0) {
      o[6] = (v - 2.f * S3) * invN;  // wire6 = reg bit3; v(lane0) = sum(tot)
      o[7] = (v - 2.f * S2) * invN;
      o[8] = (v - 2.f * S1) * invN;
      o[9] = (v - 2.f * S0) * invN;
    }
  }
}

extern "C" void kernel_launch(void* const* d_in, const int* in_sizes, int n_in,
                              void* d_out, int out_size, void* d_ws, size_t ws_size,
                              hipStream_t stream) {
  const float* x = (const float*)d_in[0];
  const float* w = (const float*)d_in[1];
  float* out = (float*)d_out;
  const int batch = in_sizes[0] / NA;
  const int waves = (batch + ELEMS - 1) / ELEMS;
  const int wavesPerBlock = 4;  // 256 threads
  const int blocks = (waves + wavesPerBlock - 1) / wavesPerBlock;
  qsim_kernel<<<blocks, 256, 0, stream>>>(x, w, out, batch);
}